// Round 5
// baseline (2066.321 us; speedup 1.0000x reference)
//
#include <hip/hip_runtime.h>

#define NN 50000
#define NE 800000
#define NH 64
#define NG 500
#define NPAD 50176   // 196*256
#define NBKT 782     // ceil(NN/64) 64-node buckets

// ---------------- degree histogram / normalization ----------------

__global__ __launch_bounds__(256) void k_hist(const int* __restrict__ dst, int* __restrict__ deg) {
  int e = blockIdx.x * 256 + threadIdx.x;
  if (e < NE) atomicAdd(&deg[dst[e]], 1);
}

__global__ __launch_bounds__(256) void k_dinv(const int* __restrict__ deg, float* __restrict__ dinv) {
  int i = blockIdx.x * 256 + threadIdx.x;
  if (i < NN) dinv[i] = rsqrtf((float)(deg[i] + 1));  // +1 self-loop
}

// ---------------- bucket counts (64 nodes / bucket) ----------------

__global__ __launch_bounds__(256) void k_bcnt(const int* __restrict__ deg, int* __restrict__ bcnt) {
  int lane = threadIdx.x & 63;
  int b = blockIdx.x * 4 + (threadIdx.x >> 6);
  if (b >= NBKT) return;
  int v = deg[b * 64 + lane];  // deg zero-padded to NPAD
#pragma unroll
  for (int off = 32; off > 0; off >>= 1) v += __shfl_down(v, off, 64);
  if (lane == 0) bcnt[b] = v;
}

// ---------------- bucket exclusive scan (single block, 4 elems/thread) ----------------

__global__ __launch_bounds__(256) void k_bscan(const int* __restrict__ bcnt, int* __restrict__ bptr,
                                               int* __restrict__ bcur) {
  __shared__ int s[256];
  int t = threadIdx.x;
  int base = t * 4;
  int v0 = (base + 0 < NBKT) ? bcnt[base + 0] : 0;
  int v1 = (base + 1 < NBKT) ? bcnt[base + 1] : 0;
  int v2 = (base + 2 < NBKT) ? bcnt[base + 2] : 0;
  int v3 = (base + 3 < NBKT) ? bcnt[base + 3] : 0;
  int lsum = v0 + v1 + v2 + v3;
  s[t] = lsum;
  __syncthreads();
#pragma unroll
  for (int off = 1; off < 256; off <<= 1) {
    int x = (t >= off) ? s[t - off] : 0;
    __syncthreads();
    s[t] += x;
    __syncthreads();
  }
  int pre = s[t] - lsum;  // exclusive prefix of this thread's group
  int p0 = pre, p1 = pre + v0, p2 = p1 + v1, p3 = p2 + v2;
  if (base + 0 < NBKT) { bptr[base + 0] = p0; bcur[base + 0] = p0; }
  if (base + 1 < NBKT) { bptr[base + 1] = p1; bcur[base + 1] = p1; }
  if (base + 2 < NBKT) { bptr[base + 2] = p2; bcur[base + 2] = p2; }
  if (base + 3 < NBKT) { bptr[base + 3] = p3; bcur[base + 3] = p3; }
  if (t == 255) bptr[NBKT] = s[255];  // == NE
}

// ---------------- binning: col[] = edges grouped by 64-node dst bucket ----------------
// word = (src<<6) | (dst&63). Two passes over this block's 8192-edge chunk:
// LDS histogram -> one global-atomic bulk reserve per (block,bucket) -> rank writes.
// Runs per (block,bucket) are contiguous -> line-dense writes (kills the 16x amp).

__global__ __launch_bounds__(256) void k_bin(const int* __restrict__ src, const int* __restrict__ dst,
                                             int* __restrict__ bcur, int* __restrict__ col) {
  __shared__ int hist[NBKT];
  __shared__ int gbase[NBKT];
  int t = threadIdx.x;
  for (int b = t; b < NBKT; b += 256) hist[b] = 0;
  __syncthreads();
  int e0 = blockIdx.x * 8192;
#pragma unroll
  for (int i = 0; i < 32; i++) {
    int e = e0 + i * 256 + t;
    if (e < NE) atomicAdd(&hist[dst[e] >> 6], 1);
  }
  __syncthreads();
  for (int b = t; b < NBKT; b += 256) {
    int c = hist[b];
    gbase[b] = c ? atomicAdd(&bcur[b], c) : 0;
    hist[b] = 0;  // reuse as rank counter
  }
  __syncthreads();
#pragma unroll
  for (int i = 0; i < 32; i++) {
    int e = e0 + i * 256 + t;
    if (e < NE) {
      int s = src[e], d = dst[e];
      int b = d >> 6;
      int r = atomicAdd(&hist[b], 1);
      col[gbase[b] + r] = (s << 6) | (d & 63);
    }
  }
}

// ---------------- graph segment pointers from sorted batch (no atomics) ----------------

__global__ __launch_bounds__(256) void k_gptr(const int* __restrict__ batch, int* __restrict__ gptr) {
  int i = blockIdx.x * 256 + threadIdx.x;
  if (i >= NN) return;
  int bi = batch[i];
  int bp = (i > 0) ? batch[i - 1] : -1;
  for (int g = bp + 1; g <= bi; g++) gptr[g] = i;
  if (i == NN - 1) {
    for (int g = bi + 1; g <= NG; g++) gptr[g] = NN;
  }
}

// ---------------- encoder: X0 = [x|pos] @ enc_W + enc_b ----------------

__global__ __launch_bounds__(256) void k_encoder(const float* __restrict__ x, const float* __restrict__ pos,
                                                 const float* __restrict__ W, const float* __restrict__ b,
                                                 float* __restrict__ X0) {
  __shared__ float Ws[16 * 64];
  __shared__ float bs[64];
  int t = threadIdx.x;
  for (int i = t; i < 1024; i += 256) Ws[i] = W[i];
  if (t < 64) bs[t] = b[t];
  __syncthreads();
  int n = blockIdx.x * 4 + (t >> 6);
  int h = t & 63;
  if (n >= NN) return;
  float acc = bs[h];
#pragma unroll
  for (int f = 0; f < 14; f++) acc += x[n * 14 + f] * Ws[f * 64 + h];
  acc += pos[n * 2 + 0] * Ws[14 * 64 + h];
  acc += pos[n * 2 + 1] * Ws[15 * 64 + h];
  X0[n * 64 + h] = acc;
}

// ---------------- fused dual GEMM + epilogue ----------------
// hWs = dinv[n] * (relu?(X) @ conv_W)            (dinv folded in: gather sums hWs)
// agg = relu?(X) @ res_W + res_b + conv_b + dinv[n] * hWs[n]   (self-loop folded in)

__global__ __launch_bounds__(256) void k_gemm_dual(const float* __restrict__ Xin,
                                                   const float* __restrict__ Wc, const float* __restrict__ Wr,
                                                   const float* __restrict__ cb, const float* __restrict__ rb,
                                                   const float* __restrict__ dinv,
                                                   float* __restrict__ hWs, float* __restrict__ agg,
                                                   int apply_relu) {
  __shared__ float Xs[128 * 64];
  __shared__ float Wcs[64 * 64];
  __shared__ float Wrs[64 * 64];
  int t = threadIdx.x;
  for (int i = t; i < 4096; i += 256) { Wcs[i] = Wc[i]; Wrs[i] = Wr[i]; }
  int n0 = blockIdx.x * 128;
#pragma unroll
  for (int i = 0; i < 8; i++) {
    int idx = t + i * 256;        // float4 index in 128x64 tile (2048 total)
    int n = idx >> 4;             // 16 float4 per row
    int kg = (idx & 15) << 2;     // k offset of float4
    float4 v = make_float4(0.f, 0.f, 0.f, 0.f);
    int gn = n0 + n;
    if (gn < NN) v = *(const float4*)(Xin + gn * 64 + kg);
    if (apply_relu) {
      v.x = fmaxf(v.x, 0.f); v.y = fmaxf(v.y, 0.f);
      v.z = fmaxf(v.z, 0.f); v.w = fmaxf(v.w, 0.f);
    }
    int sw = ((n >> 3) & 7) << 2;  // bank swizzle (float4-preserving)
    *(float4*)(Xs + n * 64 + (kg ^ sw)) = v;
  }
  __syncthreads();

  int hg = (t & 15) << 2;   // h0 (4 consecutive h)
  int ng = t >> 4;          // node group
  int nb = ng << 3;         // local node base (8 nodes)
  int swz = (ng & 7) << 2;  // matches write swizzle: rows nb..nb+7 all have row>>3 == ng

  float aC[8][4] = {};
  float aR[8][4] = {};
#pragma unroll 4
  for (int k = 0; k < 64; k++) {
    float4 wc = *(const float4*)(Wcs + k * 64 + hg);
    float4 wr = *(const float4*)(Wrs + k * 64 + hg);
    int kk = k ^ swz;
#pragma unroll
    for (int i = 0; i < 8; i++) {
      float xv = Xs[(nb + i) * 64 + kk];
      aC[i][0] += xv * wc.x; aC[i][1] += xv * wc.y; aC[i][2] += xv * wc.z; aC[i][3] += xv * wc.w;
      aR[i][0] += xv * wr.x; aR[i][1] += xv * wr.y; aR[i][2] += xv * wr.z; aR[i][3] += xv * wr.w;
    }
  }

  float4 cbv = *(const float4*)(cb + hg);
  float4 rbv = *(const float4*)(rb + hg);
#pragma unroll
  for (int i = 0; i < 8; i++) {
    int n = n0 + nb + i;
    if (n < NN) {
      float dv = dinv[n];
      float4 hv;
      hv.x = dv * aC[i][0]; hv.y = dv * aC[i][1]; hv.z = dv * aC[i][2]; hv.w = dv * aC[i][3];
      *(float4*)(hWs + n * 64 + hg) = hv;
      float4 av;
      av.x = aR[i][0] + rbv.x + cbv.x + dv * hv.x;
      av.y = aR[i][1] + rbv.y + cbv.y + dv * hv.y;
      av.z = aR[i][2] + rbv.z + cbv.z + dv * hv.z;
      av.w = aR[i][3] + rbv.w + cbv.w + dv * hv.w;
      *(float4*)(agg + n * 64 + hg) = av;
    }
  }
}

// ---------------- binned gather: one block per 64-node bucket ----------------
// LDS tile[64n x 64h]; edges coalesced-load + shuffle-broadcast; 8 hWs loads in
// flight; ds_add_f32 accumulate (lane-consecutive -> conflict-free). Epilogue
// adds dinv[n]*tile into agg (float4); last layer fuses decode GEMV -> Xo.

__global__ __launch_bounds__(256) void k_gather_b(const int* __restrict__ bptr, const int* __restrict__ col,
                                                  const float* __restrict__ dinv, const float* __restrict__ hWs,
                                                  float* __restrict__ agg,
                                                  const float* __restrict__ decW, float* __restrict__ Xo,
                                                  int last) {
  __shared__ float tile[64 * 64];
  int t = threadIdx.x;
  int lane = t & 63;
  int wid = t >> 6;
  int b = blockIdx.x;
#pragma unroll
  for (int j = 0; j < 4; j++) ((float4*)tile)[t + j * 256] = make_float4(0.f, 0.f, 0.f, 0.f);
  __syncthreads();

  int st = bptr[b], en = bptr[b + 1];
  for (int base = st + wid * 64; base < en; base += 256) {
    int cnt = en - base;
    if (cnt > 64) cnt = 64;
    int li = lane < cnt ? lane : cnt - 1;
    int w = col[base + li];  // one coalesced load of up to 64 packed edges
    for (int j = 0; j < cnt; j += 8) {
      int c = cnt - j;
      int w0 = __shfl(w, j, 64);
      int w1 = __shfl(w, c > 1 ? j + 1 : j, 64);
      int w2 = __shfl(w, c > 2 ? j + 2 : j, 64);
      int w3 = __shfl(w, c > 3 ? j + 3 : j, 64);
      int w4 = __shfl(w, c > 4 ? j + 4 : j, 64);
      int w5 = __shfl(w, c > 5 ? j + 5 : j, 64);
      int w6 = __shfl(w, c > 6 ? j + 6 : j, 64);
      int w7 = __shfl(w, c > 7 ? j + 7 : j, 64);
      float v0 = hWs[(w0 >> 6) * 64 + lane];
      float v1 = hWs[(w1 >> 6) * 64 + lane];
      float v2 = hWs[(w2 >> 6) * 64 + lane];
      float v3 = hWs[(w3 >> 6) * 64 + lane];
      float v4 = hWs[(w4 >> 6) * 64 + lane];
      float v5 = hWs[(w5 >> 6) * 64 + lane];
      float v6 = hWs[(w6 >> 6) * 64 + lane];
      float v7 = hWs[(w7 >> 6) * 64 + lane];
      atomicAdd(&tile[(w0 & 63) * 64 + lane], v0);
      if (c > 1) atomicAdd(&tile[(w1 & 63) * 64 + lane], v1);
      if (c > 2) atomicAdd(&tile[(w2 & 63) * 64 + lane], v2);
      if (c > 3) atomicAdd(&tile[(w3 & 63) * 64 + lane], v3);
      if (c > 4) atomicAdd(&tile[(w4 & 63) * 64 + lane], v4);
      if (c > 5) atomicAdd(&tile[(w5 & 63) * 64 + lane], v5);
      if (c > 6) atomicAdd(&tile[(w6 & 63) * 64 + lane], v6);
      if (c > 7) atomicAdd(&tile[(w7 & 63) * 64 + lane], v7);
    }
  }
  __syncthreads();

  // epilogue: agg[n] += dinv[n] * tile-row; keep result in tile for decode
#pragma unroll
  for (int j = 0; j < 4; j++) {
    int f4 = t + j * 256;           // float4 index in tile (1024 total)
    int nl = f4 >> 4;
    int n = b * 64 + nl;
    if (n < NN) {
      float dv = dinv[n];
      float4 a = *(const float4*)(agg + n * 64 + ((f4 & 15) << 2));
      float4 tl = ((float4*)tile)[f4];
      a.x += dv * tl.x; a.y += dv * tl.y; a.z += dv * tl.z; a.w += dv * tl.w;
      *(float4*)(agg + n * 64 + ((f4 & 15) << 2)) = a;
      ((float4*)tile)[f4] = a;
    }
  }
  if (last) {
    __syncthreads();
    float dW = decW[lane];
#pragma unroll
    for (int j = 0; j < 16; j++) {
      int nl = wid * 16 + j;
      int n = b * 64 + nl;
      if (n < NN) {
        float v = fmaxf(tile[nl * 64 + lane], 0.f) * dW;
#pragma unroll
        for (int off = 32; off > 0; off >>= 1) v += __shfl_down(v, off, 64);
        if (lane == 0) Xo[n] = v;
      }
    }
  }
}

// ---------------- graph pooling: out[g] = sum Xo[gptr[g]:gptr[g+1]] + cnt*decb ----------------

__global__ __launch_bounds__(256) void k_pool(const float* __restrict__ Xo, const int* __restrict__ gptr,
                                              const float* __restrict__ decb, float* __restrict__ out) {
  __shared__ float part[4];
  int g = blockIdx.x;
  int t = threadIdx.x;
  int st = gptr[g], en = gptr[g + 1];
  float v = 0.f;
  for (int i = st + t; i < en; i += 256) v += Xo[i];
#pragma unroll
  for (int off = 32; off > 0; off >>= 1) v += __shfl_down(v, off, 64);
  if ((t & 63) == 0) part[t >> 6] = v;
  __syncthreads();
  if (t == 0) out[g] = part[0] + part[1] + part[2] + part[3] + (float)(en - st) * decb[0];
}

// ---------------- launch ----------------

extern "C" void kernel_launch(void* const* d_in, const int* in_sizes, int n_in,
                              void* d_out, int out_size, void* d_ws, size_t ws_size,
                              hipStream_t stream) {
  (void)in_sizes; (void)n_in; (void)out_size; (void)ws_size;
  const float* x     = (const float*)d_in[0];
  const float* pos   = (const float*)d_in[1];
  const int*   ei    = (const int*)d_in[2];
  const int*   batch = (const int*)d_in[3];
  const float* encW  = (const float*)d_in[4];
  const float* encb  = (const float*)d_in[5];
  const float* convW = (const float*)d_in[6];
  const float* convb = (const float*)d_in[7];
  const float* resW  = (const float*)d_in[8];
  const float* resb  = (const float*)d_in[9];
  const float* decW  = (const float*)d_in[10];
  const float* decb  = (const float*)d_in[11];
  float* out = (float*)d_out;

  const int* src = ei;       // edge_index[0]
  const int* dst = ei + NE;  // edge_index[1]

  // workspace layout (4-byte elems)
  float* ws     = (float*)d_ws;
  float* dinv   = ws;                           // [NPAD]
  int*   deg    = (int*)(ws + NPAD);            // [NPAD]
  int*   bcnt   = (int*)(ws + 2 * NPAD);        // [1024]
  int*   bptr   = (int*)(ws + 2 * NPAD + 1024); // [NBKT+1]
  int*   bcur   = (int*)(ws + 2 * NPAD + 2048); // [NBKT]
  int*   gptr   = (int*)(ws + 2 * NPAD + 3072); // [NG+1]
  float* Xo     = (float*)(ws + 2 * NPAD + 4096);  // [NPAD]
  int*   col    = (int*)(ws + 3 * NPAD + 4096);    // [NE]
  float* bufA   = (float*)(col + NE);              // [NN*NH]
  float* bufB   = bufA + NN * NH;
  float* bufC   = bufB + NN * NH;

  hipMemsetAsync(deg, 0, NPAD * sizeof(int), stream);

  k_hist<<<(NE + 255) / 256, 256, 0, stream>>>(dst, deg);
  k_dinv<<<(NN + 255) / 256, 256, 0, stream>>>(deg, dinv);
  k_bcnt<<<(NBKT + 3) / 4, 256, 0, stream>>>(deg, bcnt);
  k_bscan<<<1, 256, 0, stream>>>(bcnt, bptr, bcur);
  k_bin<<<(NE + 8191) / 8192, 256, 0, stream>>>(src, dst, bcur, col);
  k_gptr<<<(NN + 255) / 256, 256, 0, stream>>>(batch, gptr);

  k_encoder<<<(NN + 3) / 4, 256, 0, stream>>>(x, pos, encW, encb, bufA);

  float* Xc = bufA;
  float* hWb = bufB;
  float* aggb = bufC;
  for (int l = 0; l < 5; l++) {
    k_gemm_dual<<<(NN + 127) / 128, 256, 0, stream>>>(Xc, convW, resW, convb, resb, dinv, hWb, aggb, l > 0 ? 1 : 0);
    k_gather_b<<<NBKT, 256, 0, stream>>>(bptr, col, dinv, hWb, aggb, decW, Xo, l == 4 ? 1 : 0);
    float* tmp = Xc; Xc = aggb; aggb = hWb; hWb = tmp;
  }
  k_pool<<<NG, 256, 0, stream>>>(Xo, gptr, decb, out);
}

// Round 6
// 398.554 us; speedup vs baseline: 5.1846x; 5.1846x over previous
//
#include <hip/hip_runtime.h>

#define NN 50000
#define NE 800000
#define NH 64
#define NG 500
#define NPAD 50176   // 196*256
#define NBKT 782     // ceil(NN/64) 64-node buckets

// ---------------- per-bucket histogram (LDS-aggregated) ----------------

__global__ __launch_bounds__(256) void k_bhist(const int* __restrict__ dst, int* __restrict__ bcnt) {
  __shared__ int hist[NBKT];
  int t = threadIdx.x;
  for (int b = t; b < NBKT; b += 256) hist[b] = 0;
  __syncthreads();
  int e0 = blockIdx.x * 8192;
#pragma unroll
  for (int i = 0; i < 32; i++) {
    int e = e0 + i * 256 + t;
    if (e < NE) atomicAdd(&hist[dst[e] >> 6], 1);
  }
  __syncthreads();
  for (int b = t; b < NBKT; b += 256) {
    int c = hist[b];
    if (c) atomicAdd(&bcnt[b], c);
  }
}

// ---------------- bucket exclusive scan (single block, 4 elems/thread) ----------------

__global__ __launch_bounds__(256) void k_bscan(const int* __restrict__ bcnt, int* __restrict__ bptr,
                                               int* __restrict__ bcur) {
  __shared__ int s[256];
  int t = threadIdx.x;
  int base = t * 4;
  int v0 = (base + 0 < NBKT) ? bcnt[base + 0] : 0;
  int v1 = (base + 1 < NBKT) ? bcnt[base + 1] : 0;
  int v2 = (base + 2 < NBKT) ? bcnt[base + 2] : 0;
  int v3 = (base + 3 < NBKT) ? bcnt[base + 3] : 0;
  int lsum = v0 + v1 + v2 + v3;
  s[t] = lsum;
  __syncthreads();
#pragma unroll
  for (int off = 1; off < 256; off <<= 1) {
    int x = (t >= off) ? s[t - off] : 0;
    __syncthreads();
    s[t] += x;
    __syncthreads();
  }
  int pre = s[t] - lsum;
  int p0 = pre, p1 = pre + v0, p2 = p1 + v1, p3 = p2 + v2;
  if (base + 0 < NBKT) { bptr[base + 0] = p0; bcur[base + 0] = p0; }
  if (base + 1 < NBKT) { bptr[base + 1] = p1; bcur[base + 1] = p1; }
  if (base + 2 < NBKT) { bptr[base + 2] = p2; bcur[base + 2] = p2; }
  if (base + 3 < NBKT) { bptr[base + 3] = p3; bcur[base + 3] = p3; }
  if (t == 255) bptr[NBKT] = s[255];  // == NE
}

// ---------------- binning: colp[] = packed edges grouped by 64-node dst bucket ----------------
// word = (src<<6) | (dst&63). LDS histogram -> one bulk reserve per (block,bucket)
// -> rank-addressed writes. Runs are contiguous -> line-dense writes.

__global__ __launch_bounds__(256) void k_bin(const int* __restrict__ src, const int* __restrict__ dst,
                                             int* __restrict__ bcur, int* __restrict__ colp) {
  __shared__ int hist[NBKT];
  __shared__ int gbase[NBKT];
  int t = threadIdx.x;
  for (int b = t; b < NBKT; b += 256) hist[b] = 0;
  __syncthreads();
  int e0 = blockIdx.x * 8192;
#pragma unroll
  for (int i = 0; i < 32; i++) {
    int e = e0 + i * 256 + t;
    if (e < NE) atomicAdd(&hist[dst[e] >> 6], 1);
  }
  __syncthreads();
  for (int b = t; b < NBKT; b += 256) {
    int c = hist[b];
    gbase[b] = c ? atomicAdd(&bcur[b], c) : 0;
    hist[b] = 0;  // reuse as rank counter
  }
  __syncthreads();
#pragma unroll
  for (int i = 0; i < 32; i++) {
    int e = e0 + i * 256 + t;
    if (e < NE) {
      int s = src[e], d = dst[e];
      int b = d >> 6;
      int r = atomicAdd(&hist[b], 1);
      colp[gbase[b] + r] = (s << 6) | (d & 63);
    }
  }
}

// ---------------- bucket-local sort to exact CSR + deg/dinv/rowptr ----------------
// One block per bucket: reads its contiguous range, writes the SAME range permuted
// (~4 KB window, full lines) -> no write amplification. Also emits dinv & rowptr.

__global__ __launch_bounds__(256) void k_csr(const int* __restrict__ bptr, const int* __restrict__ colp,
                                             int* __restrict__ cols, float* __restrict__ dinv,
                                             int* __restrict__ rowptr) {
  __shared__ int hist[64];
  __shared__ int excl[65];
  int t = threadIdx.x;
  int b = blockIdx.x;
  int st = bptr[b], en = bptr[b + 1];
  if (t < 64) hist[t] = 0;
  __syncthreads();
  for (int e = st + t; e < en; e += 256) atomicAdd(&hist[colp[e] & 63], 1);
  __syncthreads();
  if (t == 0) {
    int run = 0;
#pragma unroll
    for (int i = 0; i < 64; i++) { excl[i] = run; run += hist[i]; }
    excl[64] = run;
  }
  __syncthreads();
  if (t < 64) {
    int n = b * 64 + t;
    rowptr[n] = st + excl[t];
    if (n < NN) dinv[n] = rsqrtf((float)(hist[t] + 1));  // +1 self-loop
    hist[t] = 0;  // reuse as cursor
  }
  if (b == NBKT - 1 && t == 64) rowptr[NBKT * 64] = en;  // == NE
  __syncthreads();
  for (int e = st + t; e < en; e += 256) {
    int w = colp[e];
    int d = w & 63;
    int r = atomicAdd(&hist[d], 1);
    cols[st + excl[d] + r] = w >> 6;
  }
}

// ---------------- graph segment pointers from sorted batch (no atomics) ----------------

__global__ __launch_bounds__(256) void k_gptr(const int* __restrict__ batch, int* __restrict__ gptr) {
  int i = blockIdx.x * 256 + threadIdx.x;
  if (i >= NN) return;
  int bi = batch[i];
  int bp = (i > 0) ? batch[i - 1] : -1;
  for (int g = bp + 1; g <= bi; g++) gptr[g] = i;
  if (i == NN - 1) {
    for (int g = bi + 1; g <= NG; g++) gptr[g] = NN;
  }
}

// ---------------- encoder: X0 = [x|pos] @ enc_W + enc_b ----------------

__global__ __launch_bounds__(256) void k_encoder(const float* __restrict__ x, const float* __restrict__ pos,
                                                 const float* __restrict__ W, const float* __restrict__ b,
                                                 float* __restrict__ X0) {
  __shared__ float Ws[16 * 64];
  __shared__ float bs[64];
  int t = threadIdx.x;
  for (int i = t; i < 1024; i += 256) Ws[i] = W[i];
  if (t < 64) bs[t] = b[t];
  __syncthreads();
  int n = blockIdx.x * 4 + (t >> 6);
  int h = t & 63;
  if (n >= NN) return;
  float acc = bs[h];
#pragma unroll
  for (int f = 0; f < 14; f++) acc += x[n * 14 + f] * Ws[f * 64 + h];
  acc += pos[n * 2 + 0] * Ws[14 * 64 + h];
  acc += pos[n * 2 + 1] * Ws[15 * 64 + h];
  X0[n * 64 + h] = acc;
}

// ---------------- fused dual GEMM + epilogue ----------------
// hWs = dinv[n] * (relu?(X) @ conv_W)            (dinv folded in: gather sums hWs)
// agg = relu?(X) @ res_W + res_b + conv_b + dinv[n] * hWs[n]   (self-loop folded in)

__global__ __launch_bounds__(256) void k_gemm_dual(const float* __restrict__ Xin,
                                                   const float* __restrict__ Wc, const float* __restrict__ Wr,
                                                   const float* __restrict__ cb, const float* __restrict__ rb,
                                                   const float* __restrict__ dinv,
                                                   float* __restrict__ hWs, float* __restrict__ agg,
                                                   int apply_relu) {
  __shared__ float Xs[128 * 64];
  __shared__ float Wcs[64 * 64];
  __shared__ float Wrs[64 * 64];
  int t = threadIdx.x;
  for (int i = t; i < 4096; i += 256) { Wcs[i] = Wc[i]; Wrs[i] = Wr[i]; }
  int n0 = blockIdx.x * 128;
#pragma unroll
  for (int i = 0; i < 8; i++) {
    int idx = t + i * 256;        // float4 index in 128x64 tile (2048 total)
    int n = idx >> 4;             // 16 float4 per row
    int kg = (idx & 15) << 2;     // k offset of float4
    float4 v = make_float4(0.f, 0.f, 0.f, 0.f);
    int gn = n0 + n;
    if (gn < NN) v = *(const float4*)(Xin + gn * 64 + kg);
    if (apply_relu) {
      v.x = fmaxf(v.x, 0.f); v.y = fmaxf(v.y, 0.f);
      v.z = fmaxf(v.z, 0.f); v.w = fmaxf(v.w, 0.f);
    }
    int sw = ((n >> 3) & 7) << 2;  // bank swizzle (float4-preserving)
    *(float4*)(Xs + n * 64 + (kg ^ sw)) = v;
  }
  __syncthreads();

  int hg = (t & 15) << 2;   // h0 (4 consecutive h)
  int ng = t >> 4;          // node group
  int nb = ng << 3;         // local node base (8 nodes)
  int swz = (ng & 7) << 2;  // matches write swizzle

  float aC[8][4] = {};
  float aR[8][4] = {};
#pragma unroll 4
  for (int k = 0; k < 64; k++) {
    float4 wc = *(const float4*)(Wcs + k * 64 + hg);
    float4 wr = *(const float4*)(Wrs + k * 64 + hg);
    int kk = k ^ swz;
#pragma unroll
    for (int i = 0; i < 8; i++) {
      float xv = Xs[(nb + i) * 64 + kk];
      aC[i][0] += xv * wc.x; aC[i][1] += xv * wc.y; aC[i][2] += xv * wc.z; aC[i][3] += xv * wc.w;
      aR[i][0] += xv * wr.x; aR[i][1] += xv * wr.y; aR[i][2] += xv * wr.z; aR[i][3] += xv * wr.w;
    }
  }

  float4 cbv = *(const float4*)(cb + hg);
  float4 rbv = *(const float4*)(rb + hg);
#pragma unroll
  for (int i = 0; i < 8; i++) {
    int n = n0 + nb + i;
    if (n < NN) {
      float dv = dinv[n];
      float4 hv;
      hv.x = dv * aC[i][0]; hv.y = dv * aC[i][1]; hv.z = dv * aC[i][2]; hv.w = dv * aC[i][3];
      *(float4*)(hWs + n * 64 + hg) = hv;
      float4 av;
      av.x = aR[i][0] + rbv.x + cbv.x + dv * hv.x;
      av.y = aR[i][1] + rbv.y + cbv.y + dv * hv.y;
      av.z = aR[i][2] + rbv.z + cbv.z + dv * hv.z;
      av.w = aR[i][3] + rbv.w + cbv.w + dv * hv.w;
      *(float4*)(agg + n * 64 + hg) = av;
    }
  }
}

// ---------------- CSR gather: agg[n] += dinv[n] * sum_e hWs[cols[e]] ----------------
// One 64-lane wave per dst node (50K waves chip-wide for latency hiding); row's col
// indices loaded with ONE coalesced 64-lane load, shuffle-broadcast, 8 loads in flight.
// Last layer fuses decode GEMV: Xo[n] = relu(X_final[n]) . decW.

__global__ __launch_bounds__(256) void k_gather(const int* __restrict__ rowptr, const int* __restrict__ cols,
                                                const float* __restrict__ dinv, const float* __restrict__ hWs,
                                                float* __restrict__ agg,
                                                const float* __restrict__ decW, float* __restrict__ Xo,
                                                int last) {
  int lane = threadIdx.x & 63;
  int n = __builtin_amdgcn_readfirstlane(blockIdx.x * 4 + (threadIdx.x >> 6));
  int st = rowptr[n];
  int en = rowptr[n + 1];
  int deg = en - st;
  float acc = 0.f;
  for (int base = 0; base < deg; base += 64) {
    int cnt = deg - base;
    if (cnt > 64) cnt = 64;
    int li = lane < cnt ? lane : cnt - 1;
    int colv = cols[st + base + li];  // one coalesced row-load of up to 64 indices
    for (int j = 0; j < cnt; j += 8) {
      int c = cnt - j;  // remaining (>=1)
      int s0 = __shfl(colv, j, 64);
      int s1 = __shfl(colv, c > 1 ? j + 1 : j, 64);
      int s2 = __shfl(colv, c > 2 ? j + 2 : j, 64);
      int s3 = __shfl(colv, c > 3 ? j + 3 : j, 64);
      int s4 = __shfl(colv, c > 4 ? j + 4 : j, 64);
      int s5 = __shfl(colv, c > 5 ? j + 5 : j, 64);
      int s6 = __shfl(colv, c > 6 ? j + 6 : j, 64);
      int s7 = __shfl(colv, c > 7 ? j + 7 : j, 64);
      float v0 = hWs[s0 * 64 + lane];
      float v1 = hWs[s1 * 64 + lane];
      float v2 = hWs[s2 * 64 + lane];
      float v3 = hWs[s3 * 64 + lane];
      float v4 = hWs[s4 * 64 + lane];
      float v5 = hWs[s5 * 64 + lane];
      float v6 = hWs[s6 * 64 + lane];
      float v7 = hWs[s7 * 64 + lane];
      acc += v0;
      acc += (c > 1) ? v1 : 0.f;
      acc += (c > 2) ? v2 : 0.f;
      acc += (c > 3) ? v3 : 0.f;
      acc += (c > 4) ? v4 : 0.f;
      acc += (c > 5) ? v5 : 0.f;
      acc += (c > 6) ? v6 : 0.f;
      acc += (c > 7) ? v7 : 0.f;
    }
  }
  float r = agg[n * 64 + lane] + dinv[n] * acc;
  agg[n * 64 + lane] = r;
  if (last) {
    float v = fmaxf(r, 0.f) * decW[lane];
#pragma unroll
    for (int off = 32; off > 0; off >>= 1) v += __shfl_down(v, off, 64);
    if (lane == 0) Xo[n] = v;
  }
}

// ---------------- graph pooling: out[g] = sum Xo[gptr[g]:gptr[g+1]] + cnt*decb ----------------

__global__ __launch_bounds__(256) void k_pool(const float* __restrict__ Xo, const int* __restrict__ gptr,
                                              const float* __restrict__ decb, float* __restrict__ out) {
  __shared__ float part[4];
  int g = blockIdx.x;
  int t = threadIdx.x;
  int st = gptr[g], en = gptr[g + 1];
  float v = 0.f;
  for (int i = st + t; i < en; i += 256) v += Xo[i];
#pragma unroll
  for (int off = 32; off > 0; off >>= 1) v += __shfl_down(v, off, 64);
  if ((t & 63) == 0) part[t >> 6] = v;
  __syncthreads();
  if (t == 0) out[g] = part[0] + part[1] + part[2] + part[3] + (float)(en - st) * decb[0];
}

// ---------------- launch ----------------

extern "C" void kernel_launch(void* const* d_in, const int* in_sizes, int n_in,
                              void* d_out, int out_size, void* d_ws, size_t ws_size,
                              hipStream_t stream) {
  (void)in_sizes; (void)n_in; (void)out_size; (void)ws_size;
  const float* x     = (const float*)d_in[0];
  const float* pos   = (const float*)d_in[1];
  const int*   ei    = (const int*)d_in[2];
  const int*   batch = (const int*)d_in[3];
  const float* encW  = (const float*)d_in[4];
  const float* encb  = (const float*)d_in[5];
  const float* convW = (const float*)d_in[6];
  const float* convb = (const float*)d_in[7];
  const float* resW  = (const float*)d_in[8];
  const float* resb  = (const float*)d_in[9];
  const float* decW  = (const float*)d_in[10];
  const float* decb  = (const float*)d_in[11];
  float* out = (float*)d_out;

  const int* src = ei;       // edge_index[0]
  const int* dst = ei + NE;  // edge_index[1]

  // workspace layout (4-byte elems)
  float* ws     = (float*)d_ws;
  float* dinv   = ws;                         // [NPAD]
  int*   rowptr = (int*)(ws + NPAD);          // [NPAD+64]
  int*   bcnt   = (int*)(ws + 2 * NPAD + 64); // [1024]
  int*   bptr   = bcnt + 1024;                // [NBKT+1]
  int*   bcur   = bptr + 1024;                // [NBKT]
  int*   gptr   = bcur + 1024;                // [NG+1]
  float* Xo     = (float*)(gptr + 512);       // [NPAD]
  int*   colp   = (int*)(Xo + NPAD);          // [NE] packed (src<<6)|dstLow
  int*   cols   = colp + NE;                  // [NE] CSR-sorted src
  float* bufA   = (float*)(cols + NE);        // [NN*NH]
  float* bufB   = bufA + NN * NH;
  float* bufC   = bufB + NN * NH;

  hipMemsetAsync(bcnt, 0, 1024 * sizeof(int), stream);

  k_bhist<<<(NE + 8191) / 8192, 256, 0, stream>>>(dst, bcnt);
  k_bscan<<<1, 256, 0, stream>>>(bcnt, bptr, bcur);
  k_bin<<<(NE + 8191) / 8192, 256, 0, stream>>>(src, dst, bcur, colp);
  k_csr<<<NBKT, 256, 0, stream>>>(bptr, colp, cols, dinv, rowptr);
  k_gptr<<<(NN + 255) / 256, 256, 0, stream>>>(batch, gptr);

  k_encoder<<<(NN + 3) / 4, 256, 0, stream>>>(x, pos, encW, encb, bufA);

  float* Xc = bufA;
  float* hWb = bufB;
  float* aggb = bufC;
  for (int l = 0; l < 5; l++) {
    k_gemm_dual<<<(NN + 127) / 128, 256, 0, stream>>>(Xc, convW, resW, convb, resb, dinv, hWb, aggb, l > 0 ? 1 : 0);
    k_gather<<<NN / 4, 256, 0, stream>>>(rowptr, cols, dinv, hWb, aggb, decW, Xo, l == 4 ? 1 : 0);
    float* tmp = Xc; Xc = aggb; aggb = hWb; hWb = tmp;
  }
  k_pool<<<NG, 256, 0, stream>>>(Xo, gptr, decb, out);
}

// Round 7
// 359.698 us; speedup vs baseline: 5.7446x; 1.1080x over previous
//
#include <hip/hip_runtime.h>

#define NN 50000
#define NE 800000
#define NH 64
#define NG 500
#define NPAD 50176   // 196*256
#define NBKT 782     // ceil(NN/64) 64-node buckets

// fp32 -> bf16 round-to-nearest-even
__device__ __forceinline__ unsigned short f2bf(float f) {
  unsigned x = __float_as_uint(f);
  unsigned r = ((x >> 16) & 1u) + 0x7fffu;
  return (unsigned short)((x + r) >> 16);
}
__device__ __forceinline__ float bf2f(unsigned short u) {
  return __uint_as_float(((unsigned)u) << 16);
}

// ---------------- per-bucket histogram (LDS-aggregated) ----------------

__global__ __launch_bounds__(256) void k_bhist(const int* __restrict__ dst, int* __restrict__ bcnt) {
  __shared__ int hist[NBKT];
  int t = threadIdx.x;
  for (int b = t; b < NBKT; b += 256) hist[b] = 0;
  __syncthreads();
  int e0 = blockIdx.x * 8192;
#pragma unroll
  for (int i = 0; i < 32; i++) {
    int e = e0 + i * 256 + t;
    if (e < NE) atomicAdd(&hist[dst[e] >> 6], 1);
  }
  __syncthreads();
  for (int b = t; b < NBKT; b += 256) {
    int c = hist[b];
    if (c) atomicAdd(&bcnt[b], c);
  }
}

// ---------------- bucket exclusive scan (single block, 4 elems/thread) ----------------

__global__ __launch_bounds__(256) void k_bscan(const int* __restrict__ bcnt, int* __restrict__ bptr,
                                               int* __restrict__ bcur) {
  __shared__ int s[256];
  int t = threadIdx.x;
  int base = t * 4;
  int v0 = (base + 0 < NBKT) ? bcnt[base + 0] : 0;
  int v1 = (base + 1 < NBKT) ? bcnt[base + 1] : 0;
  int v2 = (base + 2 < NBKT) ? bcnt[base + 2] : 0;
  int v3 = (base + 3 < NBKT) ? bcnt[base + 3] : 0;
  int lsum = v0 + v1 + v2 + v3;
  s[t] = lsum;
  __syncthreads();
#pragma unroll
  for (int off = 1; off < 256; off <<= 1) {
    int x = (t >= off) ? s[t - off] : 0;
    __syncthreads();
    s[t] += x;
    __syncthreads();
  }
  int pre = s[t] - lsum;
  int p0 = pre, p1 = pre + v0, p2 = p1 + v1, p3 = p2 + v2;
  if (base + 0 < NBKT) { bptr[base + 0] = p0; bcur[base + 0] = p0; }
  if (base + 1 < NBKT) { bptr[base + 1] = p1; bcur[base + 1] = p1; }
  if (base + 2 < NBKT) { bptr[base + 2] = p2; bcur[base + 2] = p2; }
  if (base + 3 < NBKT) { bptr[base + 3] = p3; bcur[base + 3] = p3; }
  if (t == 255) bptr[NBKT] = s[255];  // == NE
}

// ---------------- binning: colp[] = packed edges grouped by 64-node dst bucket ----------------

__global__ __launch_bounds__(256) void k_bin(const int* __restrict__ src, const int* __restrict__ dst,
                                             int* __restrict__ bcur, int* __restrict__ colp) {
  __shared__ int hist[NBKT];
  __shared__ int gbase[NBKT];
  int t = threadIdx.x;
  for (int b = t; b < NBKT; b += 256) hist[b] = 0;
  __syncthreads();
  int e0 = blockIdx.x * 8192;
#pragma unroll
  for (int i = 0; i < 32; i++) {
    int e = e0 + i * 256 + t;
    if (e < NE) atomicAdd(&hist[dst[e] >> 6], 1);
  }
  __syncthreads();
  for (int b = t; b < NBKT; b += 256) {
    int c = hist[b];
    gbase[b] = c ? atomicAdd(&bcur[b], c) : 0;
    hist[b] = 0;  // reuse as rank counter
  }
  __syncthreads();
#pragma unroll
  for (int i = 0; i < 32; i++) {
    int e = e0 + i * 256 + t;
    if (e < NE) {
      int s = src[e], d = dst[e];
      int b = d >> 6;
      int r = atomicAdd(&hist[b], 1);
      colp[gbase[b] + r] = (s << 6) | (d & 63);
    }
  }
}

// ---------------- bucket-local sort to exact CSR + deg/dinv/rowptr ----------------

__global__ __launch_bounds__(256) void k_csr(const int* __restrict__ bptr, const int* __restrict__ colp,
                                             int* __restrict__ cols, float* __restrict__ dinv,
                                             int* __restrict__ rowptr) {
  __shared__ int hist[64];
  __shared__ int excl[65];
  int t = threadIdx.x;
  int b = blockIdx.x;
  int st = bptr[b], en = bptr[b + 1];
  if (t < 64) hist[t] = 0;
  __syncthreads();
  for (int e = st + t; e < en; e += 256) atomicAdd(&hist[colp[e] & 63], 1);
  __syncthreads();
  if (t == 0) {
    int run = 0;
#pragma unroll
    for (int i = 0; i < 64; i++) { excl[i] = run; run += hist[i]; }
    excl[64] = run;
  }
  __syncthreads();
  if (t < 64) {
    int n = b * 64 + t;
    rowptr[n] = st + excl[t];
    if (n < NN) dinv[n] = rsqrtf((float)(hist[t] + 1));  // +1 self-loop
    hist[t] = 0;  // reuse as cursor
  }
  if (b == NBKT - 1 && t == 64) rowptr[NBKT * 64] = en;  // == NE
  __syncthreads();
  for (int e = st + t; e < en; e += 256) {
    int w = colp[e];
    int d = w & 63;
    int r = atomicAdd(&hist[d], 1);
    cols[st + excl[d] + r] = w >> 6;
  }
}

// ---------------- graph segment pointers from sorted batch (no atomics) ----------------

__global__ __launch_bounds__(256) void k_gptr(const int* __restrict__ batch, int* __restrict__ gptr) {
  int i = blockIdx.x * 256 + threadIdx.x;
  if (i >= NN) return;
  int bi = batch[i];
  int bp = (i > 0) ? batch[i - 1] : -1;
  for (int g = bp + 1; g <= bi; g++) gptr[g] = i;
  if (i == NN - 1) {
    for (int g = bi + 1; g <= NG; g++) gptr[g] = NN;
  }
}

// ---------------- encoder: X0 = [x|pos] @ enc_W + enc_b ----------------

__global__ __launch_bounds__(256) void k_encoder(const float* __restrict__ x, const float* __restrict__ pos,
                                                 const float* __restrict__ W, const float* __restrict__ b,
                                                 float* __restrict__ X0) {
  __shared__ float Ws[16 * 64];
  __shared__ float bs[64];
  int t = threadIdx.x;
  for (int i = t; i < 1024; i += 256) Ws[i] = W[i];
  if (t < 64) bs[t] = b[t];
  __syncthreads();
  int n = blockIdx.x * 4 + (t >> 6);
  int h = t & 63;
  if (n >= NN) return;
  float acc = bs[h];
#pragma unroll
  for (int f = 0; f < 14; f++) acc += x[n * 14 + f] * Ws[f * 64 + h];
  acc += pos[n * 2 + 0] * Ws[14 * 64 + h];
  acc += pos[n * 2 + 1] * Ws[15 * 64 + h];
  X0[n * 64 + h] = acc;
}

// ---------------- fused dual GEMM + epilogue (64-node tile, 48 KB LDS -> 3 blocks/CU) ----------------
// hWbf = bf16( dinv[n] * (relu?(X) @ conv_W) )   (gather sums these)
// agg  = relu?(X) @ res_W + res_b + conv_b + dinv[n]^2 * hW_fp32[n]   (self-loop in fp32)

__global__ __launch_bounds__(256) void k_gemm_dual(const float* __restrict__ Xin,
                                                   const float* __restrict__ Wc, const float* __restrict__ Wr,
                                                   const float* __restrict__ cb, const float* __restrict__ rb,
                                                   const float* __restrict__ dinv,
                                                   unsigned short* __restrict__ hWbf, float* __restrict__ agg,
                                                   int apply_relu) {
  __shared__ float Xs[64 * 64];
  __shared__ float Wcs[64 * 64];
  __shared__ float Wrs[64 * 64];
  int t = threadIdx.x;
#pragma unroll
  for (int j = 0; j < 4; j++) {
    ((float4*)Wcs)[t + j * 256] = ((const float4*)Wc)[t + j * 256];
    ((float4*)Wrs)[t + j * 256] = ((const float4*)Wr)[t + j * 256];
  }
  int n0 = blockIdx.x * 64;
#pragma unroll
  for (int i = 0; i < 4; i++) {
    int idx = t + i * 256;        // float4 index in 64x64 tile (1024 total)
    int n = idx >> 4;             // 16 float4 per row
    int kg = (idx & 15) << 2;
    float4 v = make_float4(0.f, 0.f, 0.f, 0.f);
    int gn = n0 + n;
    if (gn < NN) v = *(const float4*)(Xin + gn * 64 + kg);
    if (apply_relu) {
      v.x = fmaxf(v.x, 0.f); v.y = fmaxf(v.y, 0.f);
      v.z = fmaxf(v.z, 0.f); v.w = fmaxf(v.w, 0.f);
    }
    int sw = ((n >> 2) & 7) << 2;  // float4-preserving bank swizzle
    *(float4*)(Xs + n * 64 + (kg ^ sw)) = v;
  }
  __syncthreads();

  int hg = (t & 15) << 2;   // h0 (4 consecutive h)
  int ng = t >> 4;          // node group (16 groups x 4 nodes)
  int nb = ng << 2;
  int swz = (ng & 7) << 2;  // rows nb..nb+3 share row>>2 == ng

  float aC[4][4] = {};
  float aR[4][4] = {};
#pragma unroll 4
  for (int k = 0; k < 64; k++) {
    float4 wc = *(const float4*)(Wcs + k * 64 + hg);
    float4 wr = *(const float4*)(Wrs + k * 64 + hg);
    int kk = k ^ swz;
#pragma unroll
    for (int i = 0; i < 4; i++) {
      float xv = Xs[(nb + i) * 64 + kk];
      aC[i][0] += xv * wc.x; aC[i][1] += xv * wc.y; aC[i][2] += xv * wc.z; aC[i][3] += xv * wc.w;
      aR[i][0] += xv * wr.x; aR[i][1] += xv * wr.y; aR[i][2] += xv * wr.z; aR[i][3] += xv * wr.w;
    }
  }

  float4 cbv = *(const float4*)(cb + hg);
  float4 rbv = *(const float4*)(rb + hg);
#pragma unroll
  for (int i = 0; i < 4; i++) {
    int n = n0 + nb + i;
    if (n < NN) {
      float dv = dinv[n];
      float4 hv;
      hv.x = dv * aC[i][0]; hv.y = dv * aC[i][1]; hv.z = dv * aC[i][2]; hv.w = dv * aC[i][3];
      ushort4 hb;
      hb.x = f2bf(hv.x); hb.y = f2bf(hv.y); hb.z = f2bf(hv.z); hb.w = f2bf(hv.w);
      *(ushort4*)(hWbf + n * 64 + hg) = hb;
      float4 av;
      av.x = aR[i][0] + rbv.x + cbv.x + dv * hv.x;
      av.y = aR[i][1] + rbv.y + cbv.y + dv * hv.y;
      av.z = aR[i][2] + rbv.z + cbv.z + dv * hv.z;
      av.w = aR[i][3] + rbv.w + cbv.w + dv * hv.w;
      *(float4*)(agg + n * 64 + hg) = av;
    }
  }
}

// ---------------- CSR gather: agg[n] += dinv[n] * sum_e bf2f(hWbf[cols[e]]) ----------------
// One 64-lane wave per dst node (50K waves for latency hiding); row col indices
// loaded with ONE coalesced load, shuffle-broadcast, 8 bf16 row-loads in flight.
// Last layer fuses decode GEMV: Xo[n] = relu(X_final[n]) . decW.

__global__ __launch_bounds__(256) void k_gather(const int* __restrict__ rowptr, const int* __restrict__ cols,
                                                const float* __restrict__ dinv,
                                                const unsigned short* __restrict__ hWbf,
                                                float* __restrict__ agg,
                                                const float* __restrict__ decW, float* __restrict__ Xo,
                                                int last) {
  int lane = threadIdx.x & 63;
  int n = __builtin_amdgcn_readfirstlane(blockIdx.x * 4 + (threadIdx.x >> 6));
  int st = rowptr[n];
  int en = rowptr[n + 1];
  int deg = en - st;
  float acc = 0.f;
  for (int base = 0; base < deg; base += 64) {
    int cnt = deg - base;
    if (cnt > 64) cnt = 64;
    int li = lane < cnt ? lane : cnt - 1;
    int colv = cols[st + base + li];  // one coalesced row-load of up to 64 indices
    for (int j = 0; j < cnt; j += 8) {
      int c = cnt - j;  // remaining (>=1)
      int s0 = __shfl(colv, j, 64);
      int s1 = __shfl(colv, c > 1 ? j + 1 : j, 64);
      int s2 = __shfl(colv, c > 2 ? j + 2 : j, 64);
      int s3 = __shfl(colv, c > 3 ? j + 3 : j, 64);
      int s4 = __shfl(colv, c > 4 ? j + 4 : j, 64);
      int s5 = __shfl(colv, c > 5 ? j + 5 : j, 64);
      int s6 = __shfl(colv, c > 6 ? j + 6 : j, 64);
      int s7 = __shfl(colv, c > 7 ? j + 7 : j, 64);
      float v0 = bf2f(hWbf[s0 * 64 + lane]);
      float v1 = bf2f(hWbf[s1 * 64 + lane]);
      float v2 = bf2f(hWbf[s2 * 64 + lane]);
      float v3 = bf2f(hWbf[s3 * 64 + lane]);
      float v4 = bf2f(hWbf[s4 * 64 + lane]);
      float v5 = bf2f(hWbf[s5 * 64 + lane]);
      float v6 = bf2f(hWbf[s6 * 64 + lane]);
      float v7 = bf2f(hWbf[s7 * 64 + lane]);
      acc += v0;
      acc += (c > 1) ? v1 : 0.f;
      acc += (c > 2) ? v2 : 0.f;
      acc += (c > 3) ? v3 : 0.f;
      acc += (c > 4) ? v4 : 0.f;
      acc += (c > 5) ? v5 : 0.f;
      acc += (c > 6) ? v6 : 0.f;
      acc += (c > 7) ? v7 : 0.f;
    }
  }
  float r = agg[n * 64 + lane] + dinv[n] * acc;
  agg[n * 64 + lane] = r;
  if (last) {
    float v = fmaxf(r, 0.f) * decW[lane];
#pragma unroll
    for (int off = 32; off > 0; off >>= 1) v += __shfl_down(v, off, 64);
    if (lane == 0) Xo[n] = v;
  }
}

// ---------------- graph pooling: out[g] = sum Xo[gptr[g]:gptr[g+1]] + cnt*decb ----------------

__global__ __launch_bounds__(256) void k_pool(const float* __restrict__ Xo, const int* __restrict__ gptr,
                                              const float* __restrict__ decb, float* __restrict__ out) {
  __shared__ float part[4];
  int g = blockIdx.x;
  int t = threadIdx.x;
  int st = gptr[g], en = gptr[g + 1];
  float v = 0.f;
  for (int i = st + t; i < en; i += 256) v += Xo[i];
#pragma unroll
  for (int off = 32; off > 0; off >>= 1) v += __shfl_down(v, off, 64);
  if ((t & 63) == 0) part[t >> 6] = v;
  __syncthreads();
  if (t == 0) out[g] = part[0] + part[1] + part[2] + part[3] + (float)(en - st) * decb[0];
}

// ---------------- launch ----------------

extern "C" void kernel_launch(void* const* d_in, const int* in_sizes, int n_in,
                              void* d_out, int out_size, void* d_ws, size_t ws_size,
                              hipStream_t stream) {
  (void)in_sizes; (void)n_in; (void)out_size; (void)ws_size;
  const float* x     = (const float*)d_in[0];
  const float* pos   = (const float*)d_in[1];
  const int*   ei    = (const int*)d_in[2];
  const int*   batch = (const int*)d_in[3];
  const float* encW  = (const float*)d_in[4];
  const float* encb  = (const float*)d_in[5];
  const float* convW = (const float*)d_in[6];
  const float* convb = (const float*)d_in[7];
  const float* resW  = (const float*)d_in[8];
  const float* resb  = (const float*)d_in[9];
  const float* decW  = (const float*)d_in[10];
  const float* decb  = (const float*)d_in[11];
  float* out = (float*)d_out;

  const int* src = ei;       // edge_index[0]
  const int* dst = ei + NE;  // edge_index[1]

  // workspace layout (4-byte elems)
  float*          ws     = (float*)d_ws;
  float*          dinv   = ws;                         // [NPAD]
  int*            rowptr = (int*)(ws + NPAD);          // [NPAD+64]
  int*            bcnt   = (int*)(ws + 2 * NPAD + 64); // [1024]
  int*            bptr   = bcnt + 1024;                // [NBKT+1]
  int*            bcur   = bptr + 1024;                // [NBKT]
  int*            gptr   = bcur + 1024;                // [NG+1]
  float*          Xo     = (float*)(gptr + 512);       // [NPAD]
  int*            colp   = (int*)(Xo + NPAD);          // [NE] packed (src<<6)|dstLow
  int*            cols   = colp + NE;                  // [NE] CSR-sorted src
  unsigned short* hWbf   = (unsigned short*)(cols + NE);  // [NPAD*64] bf16
  float*          bufA   = (float*)(hWbf + (size_t)NPAD * 64);  // [NN*NH]
  float*          bufB   = bufA + NN * NH;

  hipMemsetAsync(bcnt, 0, 1024 * sizeof(int), stream);

  k_bhist<<<(NE + 8191) / 8192, 256, 0, stream>>>(dst, bcnt);
  k_bscan<<<1, 256, 0, stream>>>(bcnt, bptr, bcur);
  k_bin<<<(NE + 8191) / 8192, 256, 0, stream>>>(src, dst, bcur, colp);
  k_csr<<<NBKT, 256, 0, stream>>>(bptr, colp, cols, dinv, rowptr);
  k_gptr<<<(NN + 255) / 256, 256, 0, stream>>>(batch, gptr);

  k_encoder<<<(NN + 3) / 4, 256, 0, stream>>>(x, pos, encW, encb, bufA);

  float* Xc = bufA;
  float* aggb = bufB;
  for (int l = 0; l < 5; l++) {
    k_gemm_dual<<<NBKT, 256, 0, stream>>>(Xc, convW, resW, convb, resb, dinv, hWbf, aggb, l > 0 ? 1 : 0);
    k_gather<<<NN / 4, 256, 0, stream>>>(rowptr, cols, dinv, hWbf, aggb, decW, Xo, l == 4 ? 1 : 0);
    float* tmp = Xc; Xc = aggb; aggb = tmp;
  }
  k_pool<<<NG, 256, 0, stream>>>(Xo, gptr, decb, out);
}